// Round 16
// baseline (289.836 us; speedup 1.0000x reference)
//
#include <hip/hip_runtime.h>
#include <hip/hip_fp16.h>

#define NFEAT 128
#define EPSV 1e-5f
#define BSH 9
#define BSZ 512    // nodes per dst-bucket
#define CHUNK 8192
#define CAP 12288  // edge capacity per bucket (avg 8163, max ~8.7k)

typedef _Float16 h8 __attribute__((ext_vector_type(8)));   // 8 halfs = 16B
typedef float f4 __attribute__((ext_vector_type(4)));

// ---- fused front: blocks [0,256) = column stats; blocks [256, 256+nchunk) = bucket
__global__ __launch_bounds__(256) void k_front(const float4* __restrict__ X4,
    float* __restrict__ part, int total4,
    const int* __restrict__ src, const int* __restrict__ dst,
    int* __restrict__ bnxt, int* __restrict__ packed, int E, int NB)
{
    __shared__ float4 ls[256], lq[256];        // stats path
    __shared__ int hist[1024], base[1024];     // bucket path
    int t = threadIdx.x;

    if (blockIdx.x < 256) {
        int stride = 256 * 256;
        int i = blockIdx.x * 256 + t;
        float4 s = make_float4(0.f, 0.f, 0.f, 0.f);
        float4 q = make_float4(0.f, 0.f, 0.f, 0.f);
        for (; i + 3 * stride < total4; i += 4 * stride) {
            float4 a = X4[i], b = X4[i + stride], c = X4[i + 2 * stride], d = X4[i + 3 * stride];
            s.x += (a.x + b.x) + (c.x + d.x);
            s.y += (a.y + b.y) + (c.y + d.y);
            s.z += (a.z + b.z) + (c.z + d.z);
            s.w += (a.w + b.w) + (c.w + d.w);
            q.x += (a.x * a.x + b.x * b.x) + (c.x * c.x + d.x * d.x);
            q.y += (a.y * a.y + b.y * b.y) + (c.y * c.y + d.y * d.y);
            q.z += (a.z * a.z + b.z * b.z) + (c.z * c.z + d.z * d.z);
            q.w += (a.w * a.w + b.w * b.w) + (c.w * c.w + d.w * d.w);
        }
        for (; i < total4; i += stride) {
            float4 a = X4[i];
            s.x += a.x; s.y += a.y; s.z += a.z; s.w += a.w;
            q.x = fmaf(a.x, a.x, q.x); q.y = fmaf(a.y, a.y, q.y);
            q.z = fmaf(a.z, a.z, q.z); q.w = fmaf(a.w, a.w, q.w);
        }
        ls[t] = s; lq[t] = q;
        __syncthreads();
        #pragma unroll
        for (int off = 128; off >= 32; off >>= 1) {
            if (t < off) {
                float4 a = ls[t], b = ls[t + off];
                ls[t] = make_float4(a.x + b.x, a.y + b.y, a.z + b.z, a.w + b.w);
                float4 c = lq[t], d = lq[t + off];
                lq[t] = make_float4(c.x + d.x, c.y + d.y, c.z + d.z, c.w + d.w);
            }
            __syncthreads();
        }
        if (t < 32) {
            float4* p4 = (float4*)(part + blockIdx.x * 256);
            p4[t] = ls[t];          // sum  cols 4t..4t+3
            p4[32 + t] = lq[t];     // sumsq
        }
    } else {
        int cb = blockIdx.x - 256;
        int c0 = cb * (CHUNK / 4);            // int4 index
        int c1 = min(E >> 2, c0 + CHUNK / 4);
        const int4* dst4 = (const int4*)dst;
        const int4* src4 = (const int4*)src;
        for (int i = t; i < NB; i += 256) hist[i] = 0;
        __syncthreads();
        for (int e = c0 + t; e < c1; e += 256) {
            int4 d = dst4[e];
            atomicAdd(&hist[d.x >> BSH], 1);
            atomicAdd(&hist[d.y >> BSH], 1);
            atomicAdd(&hist[d.z >> BSH], 1);
            atomicAdd(&hist[d.w >> BSH], 1);
        }
        __syncthreads();
        for (int i = t; i < NB; i += 256) {
            int h = hist[i];
            base[i] = h ? atomicAdd(&bnxt[i], h) : 0;
            hist[i] = 0;
        }
        __syncthreads();
        for (int e = c0 + t; e < c1; e += 256) {
            int4 d = dst4[e];
            int4 s = src4[e];
            int b, p;
            b = d.x >> BSH; p = base[b] + atomicAdd(&hist[b], 1); packed[b * CAP + p] = (s.x << BSH) | (d.x & (BSZ - 1));
            b = d.y >> BSH; p = base[b] + atomicAdd(&hist[b], 1); packed[b * CAP + p] = (s.y << BSH) | (d.y & (BSZ - 1));
            b = d.z >> BSH; p = base[b] + atomicAdd(&hist[b], 1); packed[b * CAP + p] = (s.z << BSH) | (d.z & (BSZ - 1));
            b = d.w >> BSH; p = base[b] + atomicAdd(&hist[b], 1); packed[b * CAP + p] = (s.w << BSH) | (d.w & (BSZ - 1));
        }
        if (cb == 0) {
            for (int e = (E & ~3) + t; e < E; e += 256) {
                int d = dst[e];
                int b = d >> BSH;
                int p = atomicAdd(&bnxt[b], 1);
                packed[b * CAP + p] = (src[e] << BSH) | (d & (BSZ - 1));
            }
        }
    }
}

// ---- fold BN into W1 (reduces the 256 part rows inline; no stats2 kernel) -------
__global__ __launch_bounds__(256) void k_foldW(const float* __restrict__ W1,
    const float* __restrict__ gamma, const float* __restrict__ beta,
    const float* __restrict__ part, float invN,
    float* __restrict__ W1p, float* __restrict__ c1)
{
    int o = (blockIdx.x * 256 + threadIdx.x) >> 6;
    int l = threadIdx.x & 63;
    float acc = 0.f;
    #pragma unroll
    for (int j = 0; j < 2; ++j) {
        int k = 2 * l + j;
        float sm = 0.f, sq = 0.f;
        #pragma unroll 8
        for (int b = 0; b < 256; ++b) {
            sm += part[b * 256 + k];
            sq += part[b * 256 + 128 + k];
        }
        float mu = sm * invN;
        float var = fmaf(-mu, mu, sq * invN);
        float sc = rsqrtf(var + EPSV) * gamma[k];
        float sh = fmaf(-mu, sc, beta[k]);
        float w = W1[o * NFEAT + k];
        W1p[o * NFEAT + k] = w * sc;
        acc = fmaf(sh, w, acc);
    }
    #pragma unroll
    for (int off = 32; off > 0; off >>= 1) acc += __shfl_down(acc, off);
    if (l == 0) c1[o] = acc;
}

// ---- fused mid: blocks [0,512) = GEMM1 (f32 in, NO dinv); [512,512+NB) = bdp ----
// GEMM1 depends only on W1p/c1 (stats chain); bdp only on packed/bnxt (bucket
// chain) -> they overlap in one launch. dinv is applied per-edge in k_agg<1>.
__global__ __launch_bounds__(256) void k_mid(const float4* __restrict__ X4,
    const float* __restrict__ W, const float* __restrict__ C,
    _Float16* __restrict__ Y, int N,
    const int* __restrict__ packed, const int* __restrict__ bnxt,
    int* __restrict__ rp, float* __restrict__ dinv, int* __restrict__ csr,
    int E, int NB)
{
    __shared__ _Float16 w16[NFEAT * 136];    // gemm: [o][k], stride 136 halfs
    __shared__ _Float16 ost[4 * 16 * 136];   // gemm: 4 waves x 16 rows x 136
    __shared__ int cnt[BSZ];                 // bdp
    __shared__ int ps[256];
    __shared__ int pb[256];
    int t = threadIdx.x;

    if (blockIdx.x < 512) {
        // ---------------- GEMM1: Y[n][o] = (X[n]@W^T)[o] + C[o]  (f16 out) ------
        const float4* W4 = (const float4*)W;
        for (int idx = t; idx < NFEAT * NFEAT / 4; idx += 256) {
            float4 w = W4[idx];
            int o = idx >> 5, k = (idx & 31) * 4;
            _Float16* d = &w16[o * 136 + k];
            d[0] = (_Float16)w.x; d[1] = (_Float16)w.y;
            d[2] = (_Float16)w.z; d[3] = (_Float16)w.w;
        }
        __syncthreads();
        const h8* Wv = (const h8*)w16;
        h8* Yv = (h8*)Y;
        int lane = t & 63;
        int lr = lane & 15;
        int lk = lane >> 4;
        _Float16* slab = ost + (t >> 6) * (16 * 136);
        h8* slabv = (h8*)slab;
        int wid = (blockIdx.x * 256 + t) >> 6;
        int nw = (512 * 256) >> 6;
        int ntiles = N >> 4;
        for (int tile = wid; tile < ntiles; tile += nw) {
            int r0 = tile << 4;
            h8 a[4];
            #pragma unroll
            for (int kg = 0; kg < 4; ++kg) {
                long fi = (long)(r0 + lr) * 32 + (kg * 4 + lk) * 2;
                float4 u = X4[fi];
                float4 v = X4[fi + 1];
                a[kg][0] = (_Float16)u.x; a[kg][1] = (_Float16)u.y;
                a[kg][2] = (_Float16)u.z; a[kg][3] = (_Float16)u.w;
                a[kg][4] = (_Float16)v.x; a[kg][5] = (_Float16)v.y;
                a[kg][6] = (_Float16)v.z; a[kg][7] = (_Float16)v.w;
            }
            f4 acc[8];
            #pragma unroll
            for (int nt = 0; nt < 8; ++nt) acc[nt] = (f4)(0.f);
            #pragma unroll
            for (int nt = 0; nt < 8; ++nt) {
                int o = nt * 16 + lr;
                #pragma unroll
                for (int kg = 0; kg < 4; ++kg) {
                    h8 b = Wv[o * 17 + kg * 4 + lk];
                    acc[nt] = __builtin_amdgcn_mfma_f32_16x16x32_f16(a[kg], b, acc[nt], 0, 0, 0);
                }
            }
            int rbase = lk * 4;
            #pragma unroll
            for (int nt = 0; nt < 8; ++nt) {
                int c = nt * 16 + lr;
                float cb = C[c];
                slab[(rbase + 0) * 136 + c] = (_Float16)(acc[nt][0] + cb);
                slab[(rbase + 1) * 136 + c] = (_Float16)(acc[nt][1] + cb);
                slab[(rbase + 2) * 136 + c] = (_Float16)(acc[nt][2] + cb);
                slab[(rbase + 3) * 136 + c] = (_Float16)(acc[nt][3] + cb);
            }
            #pragma unroll
            for (int j = 0; j < 4; ++j) {
                int row = j * 4 + lk;
                Yv[(long)(r0 + row) * 16 + lr] = slabv[row * 17 + lr];
            }
        }
    } else {
        // ---------------- bdp: scan bnxt -> degree -> rp/dinv -> CSR place ------
        int b = blockIdx.x - 512;
        cnt[2 * t] = 0; cnt[2 * t + 1] = 0;
        int v = (t < NB) ? bnxt[t] : 0;
        pb[t] = v;
        __syncthreads();
        #pragma unroll
        for (int off = 1; off < 256; off <<= 1) {
            int u = pb[t];
            if (t >= off) u += pb[t - off];
            __syncthreads();
            pb[t] = u;
            __syncthreads();
        }
        int boffb = (b == 0) ? 0 : pb[b - 1];
        int ecnt = bnxt[b];
        const int* pk = packed + b * CAP;
        const int4* p4 = (const int4*)pk;
        int n4 = ecnt >> 2;
        for (int e = t; e < n4; e += 256) {
            int4 w = p4[e];
            atomicAdd(&cnt[w.x & (BSZ - 1)], 1);
            atomicAdd(&cnt[w.y & (BSZ - 1)], 1);
            atomicAdd(&cnt[w.z & (BSZ - 1)], 1);
            atomicAdd(&cnt[w.w & (BSZ - 1)], 1);
        }
        for (int e = (n4 << 2) + t; e < ecnt; e += 256)
            atomicAdd(&cnt[pk[e] & (BSZ - 1)], 1);
        __syncthreads();
        int v0 = cnt[2 * t], v1 = cnt[2 * t + 1];
        int ts = v0 + v1;
        ps[t] = ts;
        __syncthreads();
        #pragma unroll
        for (int off = 1; off < 256; off <<= 1) {
            int u = ps[t];
            if (t >= off) u += ps[t - off];
            __syncthreads();
            ps[t] = u;
            __syncthreads();
        }
        int gbase = boffb + ps[t] - ts;
        cnt[2 * t] = gbase;
        cnt[2 * t + 1] = gbase + v0;
        int nbase = b << BSH;
        if (nbase + 2 * t < N) {
            rp[nbase + 2 * t] = gbase;
            dinv[nbase + 2 * t] = rsqrtf((float)(v0 + 1));
        }
        if (nbase + 2 * t + 1 < N) {
            rp[nbase + 2 * t + 1] = gbase + v0;
            dinv[nbase + 2 * t + 1] = rsqrtf((float)(v1 + 1));
        }
        if (b == 0 && t == 0) rp[N] = E;
        __syncthreads();
        for (int e = t; e < n4; e += 256) {
            int4 w = p4[e];
            int p;
            p = atomicAdd(&cnt[w.x & (BSZ - 1)], 1); csr[p] = w.x >> BSH;
            p = atomicAdd(&cnt[w.y & (BSZ - 1)], 1); csr[p] = w.y >> BSH;
            p = atomicAdd(&cnt[w.z & (BSZ - 1)], 1); csr[p] = w.z >> BSH;
            p = atomicAdd(&cnt[w.w & (BSZ - 1)], 1); csr[p] = w.w >> BSH;
        }
        for (int e = (n4 << 2) + t; e < ecnt; e += 256) {
            int w = pk[e];
            int p = atomicAdd(&cnt[w & (BSZ - 1)], 1);
            csr[p] = w >> BSH;
        }
    }
}

// ---- MFMA GEMM, f16 input (layer 2): Y[n][o] = dinv[n]*(X[n]@W^T)[o] -----------
__global__ __launch_bounds__(256) void k_gemm_f16(const _Float16* __restrict__ X,
    const float* __restrict__ W, const float* __restrict__ dinv,
    _Float16* __restrict__ Y, int N)
{
    __shared__ _Float16 w16[NFEAT * 136];
    __shared__ _Float16 ost[4 * 16 * 136];
    const float4* W4 = (const float4*)W;
    for (int idx = threadIdx.x; idx < NFEAT * NFEAT / 4; idx += 256) {
        float4 w = W4[idx];
        int o = idx >> 5, k = (idx & 31) * 4;
        _Float16* d = &w16[o * 136 + k];
        d[0] = (_Float16)w.x; d[1] = (_Float16)w.y;
        d[2] = (_Float16)w.z; d[3] = (_Float16)w.w;
    }
    __syncthreads();

    const h8* Xv = (const h8*)X;
    const h8* Wv = (const h8*)w16;
    h8* Yv = (h8*)Y;
    int lane = threadIdx.x & 63;
    int lr = lane & 15;
    int lk = lane >> 4;
    _Float16* slab = ost + (threadIdx.x >> 6) * (16 * 136);
    h8* slabv = (h8*)slab;
    int wid = (blockIdx.x * blockDim.x + threadIdx.x) >> 6;
    int nw = (gridDim.x * blockDim.x) >> 6;
    int ntiles = N >> 4;

    for (int tile = wid; tile < ntiles; tile += nw) {
        int r0 = tile << 4;
        h8 a[4];
        #pragma unroll
        for (int kg = 0; kg < 4; ++kg)
            a[kg] = Xv[(long)(r0 + lr) * 16 + kg * 4 + lk];

        f4 acc[8];
        #pragma unroll
        for (int nt = 0; nt < 8; ++nt) acc[nt] = (f4)(0.f);
        #pragma unroll
        for (int nt = 0; nt < 8; ++nt) {
            int o = nt * 16 + lr;
            #pragma unroll
            for (int kg = 0; kg < 4; ++kg) {
                h8 b = Wv[o * 17 + kg * 4 + lk];
                acc[nt] = __builtin_amdgcn_mfma_f32_16x16x32_f16(a[kg], b, acc[nt], 0, 0, 0);
            }
        }

        int rbase = lk * 4;
        float dv0 = dinv[r0 + rbase + 0];
        float dv1 = dinv[r0 + rbase + 1];
        float dv2 = dinv[r0 + rbase + 2];
        float dv3 = dinv[r0 + rbase + 3];
        #pragma unroll
        for (int nt = 0; nt < 8; ++nt) {
            int c = nt * 16 + lr;
            slab[(rbase + 0) * 136 + c] = (_Float16)(acc[nt][0] * dv0);
            slab[(rbase + 1) * 136 + c] = (_Float16)(acc[nt][1] * dv1);
            slab[(rbase + 2) * 136 + c] = (_Float16)(acc[nt][2] * dv2);
            slab[(rbase + 3) * 136 + c] = (_Float16)(acc[nt][3] * dv3);
        }
        #pragma unroll
        for (int j = 0; j < 4; ++j) {
            int row = j * 4 + lk;
            Yv[(long)(r0 + row) * 16 + lr] = slabv[row * 17 + lr];
        }
    }
}

// ---- aggregation: one wave per dst node; SRCDINV=1 applies dinv[src] per edge ---
template<int SRCDINV>
__global__ __launch_bounds__(256) void k_agg(const unsigned int* __restrict__ TT,
    const int* __restrict__ rp, const int* __restrict__ csr,
    const float* __restrict__ dinv, const float* __restrict__ bias,
    unsigned int* __restrict__ OUT, int N)
{
    int wid = (blockIdx.x * 256 + threadIdx.x) >> 6;
    if (wid >= N) return;
    int lane = threadIdx.x & 63;
    float dvw = dinv[wid];
    unsigned int sv = TT[wid * 64 + lane];
    float2 sf = __half22float2(*(const __half2*)&sv);
    float2 acc;                                  // self-loop term
    if (SRCDINV) { acc.x = sf.x * dvw; acc.y = sf.y * dvw; }
    else         { acc = sf; }
    int e = rp[wid], e1 = rp[wid + 1];
    for (; e + 16 <= e1; e += 16) {
        int si[16];
        #pragma unroll
        for (int j = 0; j < 16; ++j) si[j] = csr[e + j];
        unsigned int v[16];
        #pragma unroll
        for (int j = 0; j < 16; ++j) v[j] = TT[si[j] * 64 + lane];
        float dv16[16];
        if (SRCDINV) {
            #pragma unroll
            for (int j = 0; j < 16; ++j) dv16[j] = dinv[si[j]];
        }
        float ax = 0.f, ay = 0.f;
        #pragma unroll
        for (int j = 0; j < 16; ++j) {
            float2 f = __half22float2(*(const __half2*)&v[j]);
            if (SRCDINV) { ax = fmaf(f.x, dv16[j], ax); ay = fmaf(f.y, dv16[j], ay); }
            else         { ax += f.x; ay += f.y; }
        }
        acc.x += ax; acc.y += ay;
    }
    for (; e + 8 <= e1; e += 8) {
        int si[8];
        #pragma unroll
        for (int j = 0; j < 8; ++j) si[j] = csr[e + j];
        unsigned int v[8];
        #pragma unroll
        for (int j = 0; j < 8; ++j) v[j] = TT[si[j] * 64 + lane];
        float dv8[8];
        if (SRCDINV) {
            #pragma unroll
            for (int j = 0; j < 8; ++j) dv8[j] = dinv[si[j]];
        }
        float ax = 0.f, ay = 0.f;
        #pragma unroll
        for (int j = 0; j < 8; ++j) {
            float2 f = __half22float2(*(const __half2*)&v[j]);
            if (SRCDINV) { ax = fmaf(f.x, dv8[j], ax); ay = fmaf(f.y, dv8[j], ay); }
            else         { ax += f.x; ay += f.y; }
        }
        acc.x += ax; acc.y += ay;
    }
    for (; e < e1; ++e) {
        int s = csr[e];
        unsigned int v = TT[s * 64 + lane];
        float2 f = __half22float2(*(const __half2*)&v);
        if (SRCDINV) {
            float dv = dinv[s];
            acc.x = fmaf(f.x, dv, acc.x); acc.y = fmaf(f.y, dv, acc.y);
        } else {
            acc.x += f.x; acc.y += f.y;
        }
    }
    float ox = fmaxf(fmaf(acc.x, dvw, bias[lane * 2 + 0]), 0.f);
    float oy = fmaxf(fmaf(acc.y, dvw, bias[lane * 2 + 1]), 0.f);
    __half2 o2 = __floats2half2_rn(ox, oy);
    OUT[wid * 64 + lane] = *(unsigned int*)&o2;
}

// ---------------- fused head: relu(H@Wc1^T + bc1) @ Wc2^T + bc2  (H f16) ---------
__global__ __launch_bounds__(256) void k_head(const __half* __restrict__ H,
    const float* __restrict__ Wc1, const float* __restrict__ bc1,
    const float* __restrict__ Wc2, const float* __restrict__ bc2,
    float* __restrict__ OUT, int N)
{
    __shared__ float w1[16][132];
    __shared__ float hs[16][132];
    __shared__ float h16[16][17];
    const float4* Wc14 = (const float4*)Wc1;
    for (int idx = threadIdx.x; idx < 16 * NFEAT / 4; idx += 256) {
        float4 w = Wc14[idx];
        int o = idx >> 5, k = (idx & 31) * 4;
        w1[o][k] = w.x; w1[o][k + 1] = w.y; w1[o][k + 2] = w.z; w1[o][k + 3] = w.w;
    }
    const uint4* Hu4 = (const uint4*)H;     // 16 uint4 per 128-f16 row
    int ntiles = (N + 15) >> 4;
    for (int tile = blockIdx.x; tile < ntiles; tile += gridDim.x) {
        int row0 = tile << 4;
        __syncthreads();   // also covers w1 init on first iter
        {
            int r = threadIdx.x >> 4, p = threadIdx.x & 15;
            int row = row0 + r;
            uint4 v = (row < N) ? Hu4[(long)row * 16 + p] : make_uint4(0, 0, 0, 0);
            float2 f0 = __half22float2(*(const __half2*)&v.x);
            float2 f1 = __half22float2(*(const __half2*)&v.y);
            float2 f2 = __half22float2(*(const __half2*)&v.z);
            float2 f3 = __half22float2(*(const __half2*)&v.w);
            int c = p * 8;
            hs[r][c + 0] = f0.x; hs[r][c + 1] = f0.y;
            hs[r][c + 2] = f1.x; hs[r][c + 3] = f1.y;
            hs[r][c + 4] = f2.x; hs[r][c + 5] = f2.y;
            hs[r][c + 6] = f3.x; hs[r][c + 7] = f3.y;
        }
        __syncthreads();
        int r = threadIdx.x >> 4, o = threadIdx.x & 15;
        float acc = 0.f;
        #pragma unroll 8
        for (int k = 0; k < NFEAT; ++k) acc = fmaf(hs[r][k], w1[o][k], acc);
        h16[r][o] = fmaxf(acc + bc1[o], 0.f);
        __syncthreads();
        if (threadIdx.x < 32) {
            int rr = threadIdx.x >> 1, j = threadIdx.x & 1;
            float a = bc2[j];
            #pragma unroll
            for (int o2 = 0; o2 < 16; ++o2) a = fmaf(h16[rr][o2], Wc2[j * 16 + o2], a);
            int row = row0 + rr;
            if (row < N) OUT[(long)row * 2 + j] = a;
        }
        __syncthreads();
    }
}

extern "C" void kernel_launch(void* const* d_in, const int* in_sizes, int n_in,
                              void* d_out, int out_size, void* d_ws, size_t ws_size,
                              hipStream_t stream) {
    const float* x     = (const float*)d_in[0];
    const int*   ei    = (const int*)d_in[1];
    const float* gamma = (const float*)d_in[2];
    const float* beta  = (const float*)d_in[3];
    const float* W1    = (const float*)d_in[4];
    const float* b1    = (const float*)d_in[5];
    const float* W2    = (const float*)d_in[6];
    const float* b2    = (const float*)d_in[7];
    const float* Wc1   = (const float*)d_in[8];
    const float* bc1   = (const float*)d_in[9];
    const float* Wc2   = (const float*)d_in[10];
    const float* bc2   = (const float*)d_in[11];

    int N = in_sizes[0] / NFEAT;
    int E = in_sizes[1] / 2;
    const int* srcI = ei;
    const int* dstI = ei + E;
    int NB = (N + BSZ - 1) >> BSH;   // 196 for N=100k (<=256 required)

    char* ws = (char*)d_ws;
    size_t off = 0;
    auto alloc = [&](size_t bytes) {
        void* p = ws + off;
        off += bytes;
        off = (off + 511) & ~(size_t)511;
        return p;
    };
    __half* bufA  = (__half*)alloc((size_t)N * NFEAT * 2);   // h buffer
    __half* bufB  = (__half*)alloc((size_t)N * NFEAT * 2);   // t / tt buffer
    float* part   = (float*)alloc(256 * 256 * 4);            // stats partials
    float* W1p    = (float*)alloc(NFEAT * NFEAT * 4);
    float* c1     = (float*)alloc(NFEAT * 4);
    int*   rp     = (int*)alloc((size_t)(N + 1) * 4);
    float* dinv   = (float*)alloc((size_t)N * 4);
    int*   csr    = (int*)alloc((size_t)E * 4);
    int*   packed = (int*)alloc((size_t)NB * CAP * 4);
    int*   bnxt   = (int*)alloc((size_t)(NB + 1) * 4);
    (void)ws_size;

    hipMemsetAsync(bnxt, 0, (size_t)(NB + 1) * 4, stream);

    int total4 = (int)((long)N * NFEAT / 4);
    int nchunk = (E + CHUNK - 1) / CHUNK;
    int naggb = (N + 3) / 4;

    // front: stats (256 blocks) || bucket (nchunk blocks)
    k_front<<<256 + nchunk, 256, 0, stream>>>((const float4*)x, part, total4,
                                              srcI, dstI, bnxt, packed, E, NB);
    k_foldW<<<32, 256, 0, stream>>>(W1, gamma, beta, part, 1.0f / (float)N, W1p, c1);
    // mid: GEMM1 (512 blocks, no dinv) || bdp (NB blocks)
    k_mid<<<512 + NB, 256, 0, stream>>>((const float4*)x, W1p, c1,
                                        (_Float16*)bufB, N,
                                        packed, bnxt, rp, dinv, csr, E, NB);
    // layer 1 agg applies dinv[src] per edge + dinv[dst] at the end
    k_agg<1><<<naggb, 256, 0, stream>>>((const unsigned int*)bufB, rp, csr, dinv, b1, (unsigned int*)bufA, N);
    // layer 2 (proven path: GEMM applies dinv, agg plain)
    k_gemm_f16<<<512, 256, 0, stream>>>((const _Float16*)bufA, W2, dinv, (_Float16*)bufB, N);
    k_agg<0><<<naggb, 256, 0, stream>>>((const unsigned int*)bufB, rp, csr, dinv, b2, (unsigned int*)bufA, N);
    // head
    k_head<<<2048, 256, 0, stream>>>(bufA, Wc1, bc1, Wc2, bc2, (float*)d_out, N);
}

// Round 17
// 275.450 us; speedup vs baseline: 1.0522x; 1.0522x over previous
//
#include <hip/hip_runtime.h>
#include <hip/hip_fp16.h>

#define NFEAT 128
#define EPSV 1e-5f
#define BSH 9
#define BSZ 512    // nodes per dst-bucket
#define CHUNK 8192
#define CAP 12288  // edge capacity per bucket (avg 8163, max ~8.7k)

typedef _Float16 h8 __attribute__((ext_vector_type(8)));   // 8 halfs = 16B
typedef float f4 __attribute__((ext_vector_type(4)));

// ---- fused front: blocks [0,256) = column stats; blocks [256, 256+nchunk) = bucket
__global__ __launch_bounds__(256) void k_front(const float4* __restrict__ X4,
    float* __restrict__ part, int total4,
    const int* __restrict__ src, const int* __restrict__ dst,
    int* __restrict__ bnxt, int* __restrict__ packed, int E, int NB)
{
    __shared__ float4 ls[256], lq[256];        // stats path
    __shared__ int hist[1024], base[1024];     // bucket path
    int t = threadIdx.x;

    if (blockIdx.x < 256) {
        int stride = 256 * 256;
        int i = blockIdx.x * 256 + t;
        float4 s = make_float4(0.f, 0.f, 0.f, 0.f);
        float4 q = make_float4(0.f, 0.f, 0.f, 0.f);
        for (; i + 3 * stride < total4; i += 4 * stride) {
            float4 a = X4[i], b = X4[i + stride], c = X4[i + 2 * stride], d = X4[i + 3 * stride];
            s.x += (a.x + b.x) + (c.x + d.x);
            s.y += (a.y + b.y) + (c.y + d.y);
            s.z += (a.z + b.z) + (c.z + d.z);
            s.w += (a.w + b.w) + (c.w + d.w);
            q.x += (a.x * a.x + b.x * b.x) + (c.x * c.x + d.x * d.x);
            q.y += (a.y * a.y + b.y * b.y) + (c.y * c.y + d.y * d.y);
            q.z += (a.z * a.z + b.z * b.z) + (c.z * c.z + d.z * d.z);
            q.w += (a.w * a.w + b.w * b.w) + (c.w * c.w + d.w * d.w);
        }
        for (; i < total4; i += stride) {
            float4 a = X4[i];
            s.x += a.x; s.y += a.y; s.z += a.z; s.w += a.w;
            q.x = fmaf(a.x, a.x, q.x); q.y = fmaf(a.y, a.y, q.y);
            q.z = fmaf(a.z, a.z, q.z); q.w = fmaf(a.w, a.w, q.w);
        }
        ls[t] = s; lq[t] = q;
        __syncthreads();
        #pragma unroll
        for (int off = 128; off >= 32; off >>= 1) {
            if (t < off) {
                float4 a = ls[t], b = ls[t + off];
                ls[t] = make_float4(a.x + b.x, a.y + b.y, a.z + b.z, a.w + b.w);
                float4 c = lq[t], d = lq[t + off];
                lq[t] = make_float4(c.x + d.x, c.y + d.y, c.z + d.z, c.w + d.w);
            }
            __syncthreads();
        }
        if (t < 32) {
            float4* p4 = (float4*)(part + blockIdx.x * 256);
            p4[t] = ls[t];          // sum  cols 4t..4t+3
            p4[32 + t] = lq[t];     // sumsq
        }
    } else {
        int cb = blockIdx.x - 256;
        int c0 = cb * (CHUNK / 4);            // int4 index
        int c1 = min(E >> 2, c0 + CHUNK / 4);
        const int4* dst4 = (const int4*)dst;
        const int4* src4 = (const int4*)src;
        for (int i = t; i < NB; i += 256) hist[i] = 0;
        __syncthreads();
        for (int e = c0 + t; e < c1; e += 256) {
            int4 d = dst4[e];
            atomicAdd(&hist[d.x >> BSH], 1);
            atomicAdd(&hist[d.y >> BSH], 1);
            atomicAdd(&hist[d.z >> BSH], 1);
            atomicAdd(&hist[d.w >> BSH], 1);
        }
        __syncthreads();
        for (int i = t; i < NB; i += 256) {
            int h = hist[i];
            base[i] = h ? atomicAdd(&bnxt[i], h) : 0;
            hist[i] = 0;
        }
        __syncthreads();
        for (int e = c0 + t; e < c1; e += 256) {
            int4 d = dst4[e];
            int4 s = src4[e];
            int b, p;
            b = d.x >> BSH; p = base[b] + atomicAdd(&hist[b], 1); packed[b * CAP + p] = (s.x << BSH) | (d.x & (BSZ - 1));
            b = d.y >> BSH; p = base[b] + atomicAdd(&hist[b], 1); packed[b * CAP + p] = (s.y << BSH) | (d.y & (BSZ - 1));
            b = d.z >> BSH; p = base[b] + atomicAdd(&hist[b], 1); packed[b * CAP + p] = (s.z << BSH) | (d.z & (BSZ - 1));
            b = d.w >> BSH; p = base[b] + atomicAdd(&hist[b], 1); packed[b * CAP + p] = (s.w << BSH) | (d.w & (BSZ - 1));
        }
        if (cb == 0) {
            for (int e = (E & ~3) + t; e < E; e += 256) {
                int d = dst[e];
                int b = d >> BSH;
                int p = atomicAdd(&bnxt[b], 1);
                packed[b * CAP + p] = (src[e] << BSH) | (d & (BSZ - 1));
            }
        }
    }
}

// ---- fold BN into W1 (reduces the 256 part rows inline; no stats2 kernel) -------
__global__ __launch_bounds__(256) void k_foldW(const float* __restrict__ W1,
    const float* __restrict__ gamma, const float* __restrict__ beta,
    const float* __restrict__ part, float invN,
    float* __restrict__ W1p, float* __restrict__ c1)
{
    int o = (blockIdx.x * 256 + threadIdx.x) >> 6;
    int l = threadIdx.x & 63;
    float acc = 0.f;
    #pragma unroll
    for (int j = 0; j < 2; ++j) {
        int k = 2 * l + j;
        float sm = 0.f, sq = 0.f;
        #pragma unroll 8
        for (int b = 0; b < 256; ++b) {
            sm += part[b * 256 + k];
            sq += part[b * 256 + 128 + k];
        }
        float mu = sm * invN;
        float var = fmaf(-mu, mu, sq * invN);
        float sc = rsqrtf(var + EPSV) * gamma[k];
        float sh = fmaf(-mu, sc, beta[k]);
        float w = W1[o * NFEAT + k];
        W1p[o * NFEAT + k] = w * sc;
        acc = fmaf(sh, w, acc);
    }
    #pragma unroll
    for (int off = 32; off > 0; off >>= 1) acc += __shfl_down(acc, off);
    if (l == 0) c1[o] = acc;
}

// ---- fused: internal bucket-scan -> per-bucket degree -> rp/dinv -> CSR place ---
__global__ __launch_bounds__(256) void k_bdp(const int* __restrict__ packed,
    const int* __restrict__ bnxt,
    int* __restrict__ rp, float* __restrict__ dinv,
    int* __restrict__ csr, int N, int E, int NB)
{
    __shared__ int cnt[BSZ];
    __shared__ int ps[256];
    __shared__ int pb[256];
    int b = blockIdx.x, t = threadIdx.x;
    cnt[2 * t] = 0; cnt[2 * t + 1] = 0;
    int v = (t < NB) ? bnxt[t] : 0;
    pb[t] = v;
    __syncthreads();
    #pragma unroll
    for (int off = 1; off < 256; off <<= 1) {
        int u = pb[t];
        if (t >= off) u += pb[t - off];
        __syncthreads();
        pb[t] = u;
        __syncthreads();
    }
    int boffb = (b == 0) ? 0 : pb[b - 1];      // exclusive prefix at b
    int ecnt = bnxt[b];
    const int* pk = packed + b * CAP;          // CAP%4==0 -> 16B aligned
    const int4* p4 = (const int4*)pk;
    int n4 = ecnt >> 2;
    // pass 1: count
    for (int e = t; e < n4; e += 256) {
        int4 w = p4[e];
        atomicAdd(&cnt[w.x & (BSZ - 1)], 1);
        atomicAdd(&cnt[w.y & (BSZ - 1)], 1);
        atomicAdd(&cnt[w.z & (BSZ - 1)], 1);
        atomicAdd(&cnt[w.w & (BSZ - 1)], 1);
    }
    for (int e = (n4 << 2) + t; e < ecnt; e += 256)
        atomicAdd(&cnt[pk[e] & (BSZ - 1)], 1);
    __syncthreads();
    int v0 = cnt[2 * t], v1 = cnt[2 * t + 1];
    int ts = v0 + v1;
    ps[t] = ts;
    __syncthreads();
    #pragma unroll
    for (int off = 1; off < 256; off <<= 1) {
        int u = ps[t];
        if (t >= off) u += ps[t - off];
        __syncthreads();
        ps[t] = u;
        __syncthreads();
    }
    int gbase = boffb + ps[t] - ts;
    cnt[2 * t] = gbase;            // becomes nxt
    cnt[2 * t + 1] = gbase + v0;
    int nbase = b << BSH;
    if (nbase + 2 * t < N) {
        rp[nbase + 2 * t] = gbase;
        dinv[nbase + 2 * t] = rsqrtf((float)(v0 + 1));
    }
    if (nbase + 2 * t + 1 < N) {
        rp[nbase + 2 * t + 1] = gbase + v0;
        dinv[nbase + 2 * t + 1] = rsqrtf((float)(v1 + 1));
    }
    if (b == 0 && t == 0) rp[N] = E;
    __syncthreads();
    // pass 2: place
    for (int e = t; e < n4; e += 256) {
        int4 w = p4[e];
        int p;
        p = atomicAdd(&cnt[w.x & (BSZ - 1)], 1); csr[p] = w.x >> BSH;
        p = atomicAdd(&cnt[w.y & (BSZ - 1)], 1); csr[p] = w.y >> BSH;
        p = atomicAdd(&cnt[w.z & (BSZ - 1)], 1); csr[p] = w.z >> BSH;
        p = atomicAdd(&cnt[w.w & (BSZ - 1)], 1); csr[p] = w.w >> BSH;
    }
    for (int e = (n4 << 2) + t; e < ecnt; e += 256) {
        int w = pk[e];
        int p = atomicAdd(&cnt[w & (BSZ - 1)], 1);
        csr[p] = w >> BSH;
    }
}

// ---- MFMA GEMM, f32 input: Y[n][o] = dinv[n]*((X[n]@W^T)[o] + C[o]) ------------
__global__ __launch_bounds__(256) void k_gemm_f32(const float4* __restrict__ X4,
    const float* __restrict__ W, const float* __restrict__ C,
    const float* __restrict__ dinv, _Float16* __restrict__ Y, int N)
{
    __shared__ _Float16 w16[NFEAT * 136];    // [o][k], row stride 136 halfs
    __shared__ _Float16 ost[4 * 16 * 136];   // 4 waves x 16 rows x 136 halfs
    const float4* W4 = (const float4*)W;
    for (int idx = threadIdx.x; idx < NFEAT * NFEAT / 4; idx += 256) {
        float4 w = W4[idx];
        int o = idx >> 5, k = (idx & 31) * 4;
        _Float16* d = &w16[o * 136 + k];
        d[0] = (_Float16)w.x; d[1] = (_Float16)w.y;
        d[2] = (_Float16)w.z; d[3] = (_Float16)w.w;
    }
    __syncthreads();

    const h8* Wv = (const h8*)w16;          // 17 h8-chunks per row
    h8* Yv = (h8*)Y;                         // 16 h8-chunks per row
    int lane = threadIdx.x & 63;
    int lr = lane & 15;
    int lk = lane >> 4;
    _Float16* slab = ost + (threadIdx.x >> 6) * (16 * 136);
    h8* slabv = (h8*)slab;
    int wid = (blockIdx.x * blockDim.x + threadIdx.x) >> 6;
    int nw = (gridDim.x * blockDim.x) >> 6;
    int ntiles = N >> 4;

    for (int tile = wid; tile < ntiles; tile += nw) {
        int r0 = tile << 4;
        h8 a[4];
        #pragma unroll
        for (int kg = 0; kg < 4; ++kg) {
            long fi = (long)(r0 + lr) * 32 + (kg * 4 + lk) * 2;
            float4 u = X4[fi];
            float4 v = X4[fi + 1];
            a[kg][0] = (_Float16)u.x; a[kg][1] = (_Float16)u.y;
            a[kg][2] = (_Float16)u.z; a[kg][3] = (_Float16)u.w;
            a[kg][4] = (_Float16)v.x; a[kg][5] = (_Float16)v.y;
            a[kg][6] = (_Float16)v.z; a[kg][7] = (_Float16)v.w;
        }

        f4 acc[8];
        #pragma unroll
        for (int nt = 0; nt < 8; ++nt) acc[nt] = (f4)(0.f);
        #pragma unroll
        for (int nt = 0; nt < 8; ++nt) {
            int o = nt * 16 + lr;
            #pragma unroll
            for (int kg = 0; kg < 4; ++kg) {
                h8 b = Wv[o * 17 + kg * 4 + lk];
                acc[nt] = __builtin_amdgcn_mfma_f32_16x16x32_f16(a[kg], b, acc[nt], 0, 0, 0);
            }
        }

        int rbase = lk * 4;
        float dv0 = dinv[r0 + rbase + 0];
        float dv1 = dinv[r0 + rbase + 1];
        float dv2 = dinv[r0 + rbase + 2];
        float dv3 = dinv[r0 + rbase + 3];
        #pragma unroll
        for (int nt = 0; nt < 8; ++nt) {
            int c = nt * 16 + lr;
            float cb = C[c];
            slab[(rbase + 0) * 136 + c] = (_Float16)((acc[nt][0] + cb) * dv0);
            slab[(rbase + 1) * 136 + c] = (_Float16)((acc[nt][1] + cb) * dv1);
            slab[(rbase + 2) * 136 + c] = (_Float16)((acc[nt][2] + cb) * dv2);
            slab[(rbase + 3) * 136 + c] = (_Float16)((acc[nt][3] + cb) * dv3);
        }
        #pragma unroll
        for (int j = 0; j < 4; ++j) {
            int row = j * 4 + lk;
            Yv[(long)(r0 + row) * 16 + lr] = slabv[row * 17 + lr];
        }
    }
}

// ---- MFMA GEMM, f16 input (layer 2): Y[n][o] = dinv[n]*(X[n]@W^T)[o] -----------
__global__ __launch_bounds__(256) void k_gemm_f16(const _Float16* __restrict__ X,
    const float* __restrict__ W, const float* __restrict__ dinv,
    _Float16* __restrict__ Y, int N)
{
    __shared__ _Float16 w16[NFEAT * 136];
    __shared__ _Float16 ost[4 * 16 * 136];
    const float4* W4 = (const float4*)W;
    for (int idx = threadIdx.x; idx < NFEAT * NFEAT / 4; idx += 256) {
        float4 w = W4[idx];
        int o = idx >> 5, k = (idx & 31) * 4;
        _Float16* d = &w16[o * 136 + k];
        d[0] = (_Float16)w.x; d[1] = (_Float16)w.y;
        d[2] = (_Float16)w.z; d[3] = (_Float16)w.w;
    }
    __syncthreads();

    const h8* Xv = (const h8*)X;
    const h8* Wv = (const h8*)w16;
    h8* Yv = (h8*)Y;
    int lane = threadIdx.x & 63;
    int lr = lane & 15;
    int lk = lane >> 4;
    _Float16* slab = ost + (threadIdx.x >> 6) * (16 * 136);
    h8* slabv = (h8*)slab;
    int wid = (blockIdx.x * blockDim.x + threadIdx.x) >> 6;
    int nw = (gridDim.x * blockDim.x) >> 6;
    int ntiles = N >> 4;

    for (int tile = wid; tile < ntiles; tile += nw) {
        int r0 = tile << 4;
        h8 a[4];
        #pragma unroll
        for (int kg = 0; kg < 4; ++kg)
            a[kg] = Xv[(long)(r0 + lr) * 16 + kg * 4 + lk];

        f4 acc[8];
        #pragma unroll
        for (int nt = 0; nt < 8; ++nt) acc[nt] = (f4)(0.f);
        #pragma unroll
        for (int nt = 0; nt < 8; ++nt) {
            int o = nt * 16 + lr;
            #pragma unroll
            for (int kg = 0; kg < 4; ++kg) {
                h8 b = Wv[o * 17 + kg * 4 + lk];
                acc[nt] = __builtin_amdgcn_mfma_f32_16x16x32_f16(a[kg], b, acc[nt], 0, 0, 0);
            }
        }

        int rbase = lk * 4;
        float dv0 = dinv[r0 + rbase + 0];
        float dv1 = dinv[r0 + rbase + 1];
        float dv2 = dinv[r0 + rbase + 2];
        float dv3 = dinv[r0 + rbase + 3];
        #pragma unroll
        for (int nt = 0; nt < 8; ++nt) {
            int c = nt * 16 + lr;
            slab[(rbase + 0) * 136 + c] = (_Float16)(acc[nt][0] * dv0);
            slab[(rbase + 1) * 136 + c] = (_Float16)(acc[nt][1] * dv1);
            slab[(rbase + 2) * 136 + c] = (_Float16)(acc[nt][2] * dv2);
            slab[(rbase + 3) * 136 + c] = (_Float16)(acc[nt][3] * dv3);
        }
        #pragma unroll
        for (int j = 0; j < 4; ++j) {
            int row = j * 4 + lk;
            Yv[(long)(r0 + row) * 16 + lr] = slabv[row * 17 + lr];
        }
    }
}

// ---------------- aggregation: one wave per dst node; 16/8/1 gather unroll -------
// (proven round-14 form: VGPR 32, 8 waves/SIMD, ~76us)
__global__ __launch_bounds__(256) void k_agg(const unsigned int* __restrict__ TT,
    const int* __restrict__ rp, const int* __restrict__ csr,
    const float* __restrict__ dinv, const float* __restrict__ bias,
    unsigned int* __restrict__ OUT, int N)
{
    int wid = (blockIdx.x * 256 + threadIdx.x) >> 6;
    if (wid >= N) return;
    int lane = threadIdx.x & 63;
    unsigned int sv = TT[wid * 64 + lane];
    float2 acc = __half22float2(*(const __half2*)&sv);   // self-loop term
    int e = rp[wid], e1 = rp[wid + 1];
    for (; e + 16 <= e1; e += 16) {
        int si[16];
        #pragma unroll
        for (int j = 0; j < 16; ++j) si[j] = csr[e + j];
        unsigned int v[16];
        #pragma unroll
        for (int j = 0; j < 16; ++j) v[j] = TT[si[j] * 64 + lane];
        float ax = 0.f, ay = 0.f;
        #pragma unroll
        for (int j = 0; j < 16; ++j) {
            float2 f = __half22float2(*(const __half2*)&v[j]);
            ax += f.x; ay += f.y;
        }
        acc.x += ax; acc.y += ay;
    }
    for (; e + 8 <= e1; e += 8) {
        int s0 = csr[e + 0], s1 = csr[e + 1], s2 = csr[e + 2], s3 = csr[e + 3];
        int s4 = csr[e + 4], s5 = csr[e + 5], s6 = csr[e + 6], s7 = csr[e + 7];
        unsigned int v0 = TT[s0 * 64 + lane];
        unsigned int v1 = TT[s1 * 64 + lane];
        unsigned int v2 = TT[s2 * 64 + lane];
        unsigned int v3 = TT[s3 * 64 + lane];
        unsigned int v4 = TT[s4 * 64 + lane];
        unsigned int v5 = TT[s5 * 64 + lane];
        unsigned int v6 = TT[s6 * 64 + lane];
        unsigned int v7 = TT[s7 * 64 + lane];
        float2 f0 = __half22float2(*(const __half2*)&v0);
        float2 f1 = __half22float2(*(const __half2*)&v1);
        float2 f2 = __half22float2(*(const __half2*)&v2);
        float2 f3 = __half22float2(*(const __half2*)&v3);
        float2 f4_ = __half22float2(*(const __half2*)&v4);
        float2 f5 = __half22float2(*(const __half2*)&v5);
        float2 f6 = __half22float2(*(const __half2*)&v6);
        float2 f7 = __half22float2(*(const __half2*)&v7);
        acc.x += ((f0.x + f1.x) + (f2.x + f3.x)) + ((f4_.x + f5.x) + (f6.x + f7.x));
        acc.y += ((f0.y + f1.y) + (f2.y + f3.y)) + ((f4_.y + f5.y) + (f6.y + f7.y));
    }
    for (; e < e1; ++e) {
        int s = csr[e];
        unsigned int v = TT[s * 64 + lane];
        float2 f = __half22float2(*(const __half2*)&v);
        acc.x += f.x; acc.y += f.y;
    }
    float dv = dinv[wid];
    float ox = fmaxf(fmaf(acc.x, dv, bias[lane * 2 + 0]), 0.f);
    float oy = fmaxf(fmaf(acc.y, dv, bias[lane * 2 + 1]), 0.f);
    __half2 o2 = __floats2half2_rn(ox, oy);
    OUT[wid * 64 + lane] = *(unsigned int*)&o2;
}

// ---------------- fused head: relu(H@Wc1^T + bc1) @ Wc2^T + bc2  (H f16) ---------
__global__ __launch_bounds__(256) void k_head(const __half* __restrict__ H,
    const float* __restrict__ Wc1, const float* __restrict__ bc1,
    const float* __restrict__ Wc2, const float* __restrict__ bc2,
    float* __restrict__ OUT, int N)
{
    __shared__ float w1[16][132];
    __shared__ float hs[16][132];
    __shared__ float h16[16][17];
    const float4* Wc14 = (const float4*)Wc1;
    for (int idx = threadIdx.x; idx < 16 * NFEAT / 4; idx += 256) {
        float4 w = Wc14[idx];
        int o = idx >> 5, k = (idx & 31) * 4;
        w1[o][k] = w.x; w1[o][k + 1] = w.y; w1[o][k + 2] = w.z; w1[o][k + 3] = w.w;
    }
    const uint4* Hu4 = (const uint4*)H;     // 16 uint4 per 128-f16 row
    int ntiles = (N + 15) >> 4;
    for (int tile = blockIdx.x; tile < ntiles; tile += gridDim.x) {
        int row0 = tile << 4;
        __syncthreads();   // also covers w1 init on first iter
        {
            int r = threadIdx.x >> 4, p = threadIdx.x & 15;
            int row = row0 + r;
            uint4 v = (row < N) ? Hu4[(long)row * 16 + p] : make_uint4(0, 0, 0, 0);
            float2 f0 = __half22float2(*(const __half2*)&v.x);
            float2 f1 = __half22float2(*(const __half2*)&v.y);
            float2 f2 = __half22float2(*(const __half2*)&v.z);
            float2 f3 = __half22float2(*(const __half2*)&v.w);
            int c = p * 8;
            hs[r][c + 0] = f0.x; hs[r][c + 1] = f0.y;
            hs[r][c + 2] = f1.x; hs[r][c + 3] = f1.y;
            hs[r][c + 4] = f2.x; hs[r][c + 5] = f2.y;
            hs[r][c + 6] = f3.x; hs[r][c + 7] = f3.y;
        }
        __syncthreads();
        int r = threadIdx.x >> 4, o = threadIdx.x & 15;
        float acc = 0.f;
        #pragma unroll 8
        for (int k = 0; k < NFEAT; ++k) acc = fmaf(hs[r][k], w1[o][k], acc);
        h16[r][o] = fmaxf(acc + bc1[o], 0.f);
        __syncthreads();
        if (threadIdx.x < 32) {
            int rr = threadIdx.x >> 1, j = threadIdx.x & 1;
            float a = bc2[j];
            #pragma unroll
            for (int o2 = 0; o2 < 16; ++o2) a = fmaf(h16[rr][o2], Wc2[j * 16 + o2], a);
            int row = row0 + rr;
            if (row < N) OUT[(long)row * 2 + j] = a;
        }
        __syncthreads();
    }
}

extern "C" void kernel_launch(void* const* d_in, const int* in_sizes, int n_in,
                              void* d_out, int out_size, void* d_ws, size_t ws_size,
                              hipStream_t stream) {
    const float* x     = (const float*)d_in[0];
    const int*   ei    = (const int*)d_in[1];
    const float* gamma = (const float*)d_in[2];
    const float* beta  = (const float*)d_in[3];
    const float* W1    = (const float*)d_in[4];
    const float* b1    = (const float*)d_in[5];
    const float* W2    = (const float*)d_in[6];
    const float* b2    = (const float*)d_in[7];
    const float* Wc1   = (const float*)d_in[8];
    const float* bc1   = (const float*)d_in[9];
    const float* Wc2   = (const float*)d_in[10];
    const float* bc2   = (const float*)d_in[11];

    int N = in_sizes[0] / NFEAT;
    int E = in_sizes[1] / 2;
    const int* srcI = ei;
    const int* dstI = ei + E;
    int NB = (N + BSZ - 1) >> BSH;   // 196 for N=100k (<=256 required)

    char* ws = (char*)d_ws;
    size_t off = 0;
    auto alloc = [&](size_t bytes) {
        void* p = ws + off;
        off += bytes;
        off = (off + 511) & ~(size_t)511;
        return p;
    };
    __half* bufA  = (__half*)alloc((size_t)N * NFEAT * 2);   // h buffer
    __half* bufB  = (__half*)alloc((size_t)N * NFEAT * 2);   // tt buffer
    float* part   = (float*)alloc(256 * 256 * 4);            // stats partials
    float* W1p    = (float*)alloc(NFEAT * NFEAT * 4);
    float* c1     = (float*)alloc(NFEAT * 4);
    int*   rp     = (int*)alloc((size_t)(N + 1) * 4);
    float* dinv   = (float*)alloc((size_t)N * 4);
    int*   csr    = (int*)alloc((size_t)E * 4);
    int*   packed = (int*)alloc((size_t)NB * CAP * 4);
    int*   bnxt   = (int*)alloc((size_t)(NB + 1) * 4);
    (void)ws_size;

    hipMemsetAsync(bnxt, 0, (size_t)(NB + 1) * 4, stream);

    int total4 = (int)((long)N * NFEAT / 4);
    int nchunk = (E + CHUNK - 1) / CHUNK;
    int naggb = (N + 3) / 4;

    // front: stats (256 blocks) || bucket (nchunk blocks)
    k_front<<<256 + nchunk, 256, 0, stream>>>((const float4*)x, part, total4,
                                              srcI, dstI, bnxt, packed, E, NB);
    k_foldW<<<32, 256, 0, stream>>>(W1, gamma, beta, part, 1.0f / (float)N, W1p, c1);
    k_bdp<<<NB, 256, 0, stream>>>(packed, bnxt, rp, dinv, csr, N, E, NB);

    // layer 1 (BN folded into W1p/c1; reads f32 x directly)
    k_gemm_f32<<<512, 256, 0, stream>>>((const float4*)x, W1p, c1, dinv, (_Float16*)bufB, N);
    k_agg<<<naggb, 256, 0, stream>>>((const unsigned int*)bufB, rp, csr, dinv, b1, (unsigned int*)bufA, N);
    // layer 2
    k_gemm_f16<<<512, 256, 0, stream>>>((const _Float16*)bufA, W2, dinv, (_Float16*)bufB, N);
    k_agg<<<naggb, 256, 0, stream>>>((const unsigned int*)bufB, rp, csr, dinv, b2, (unsigned int*)bufA, N);
    // head
    k_head<<<2048, 256, 0, stream>>>(bufA, Wc1, bc1, Wc2, bc2, (float*)d_out, N);
}

// Round 18
// 249.794 us; speedup vs baseline: 1.1603x; 1.1027x over previous
//
#include <hip/hip_runtime.h>
#include <hip/hip_fp16.h>

#define NFEAT 128
#define EPSV 1e-5f
#define BSH 9
#define BSZ 512    // nodes per dst-bucket
#define CHUNK 8192
#define CAP 12288  // edge capacity per bucket (avg 8163, max ~8.7k)

typedef _Float16 h8 __attribute__((ext_vector_type(8)));   // 8 halfs = 16B
typedef float f4 __attribute__((ext_vector_type(4)));

// ---- fused front: blocks [0,256) = column stats; blocks [256, 256+nchunk) = bucket
__global__ __launch_bounds__(256) void k_front(const float4* __restrict__ X4,
    float* __restrict__ part, int total4,
    const int* __restrict__ src, const int* __restrict__ dst,
    int* __restrict__ bnxt, int* __restrict__ packed, int E, int NB)
{
    __shared__ float4 ls[256], lq[256];        // stats path
    __shared__ int hist[1024], base[1024];     // bucket path
    int t = threadIdx.x;

    if (blockIdx.x < 256) {
        int stride = 256 * 256;
        int i = blockIdx.x * 256 + t;
        float4 s = make_float4(0.f, 0.f, 0.f, 0.f);
        float4 q = make_float4(0.f, 0.f, 0.f, 0.f);
        for (; i + 3 * stride < total4; i += 4 * stride) {
            float4 a = X4[i], b = X4[i + stride], c = X4[i + 2 * stride], d = X4[i + 3 * stride];
            s.x += (a.x + b.x) + (c.x + d.x);
            s.y += (a.y + b.y) + (c.y + d.y);
            s.z += (a.z + b.z) + (c.z + d.z);
            s.w += (a.w + b.w) + (c.w + d.w);
            q.x += (a.x * a.x + b.x * b.x) + (c.x * c.x + d.x * d.x);
            q.y += (a.y * a.y + b.y * b.y) + (c.y * c.y + d.y * d.y);
            q.z += (a.z * a.z + b.z * b.z) + (c.z * c.z + d.z * d.z);
            q.w += (a.w * a.w + b.w * b.w) + (c.w * c.w + d.w * d.w);
        }
        for (; i < total4; i += stride) {
            float4 a = X4[i];
            s.x += a.x; s.y += a.y; s.z += a.z; s.w += a.w;
            q.x = fmaf(a.x, a.x, q.x); q.y = fmaf(a.y, a.y, q.y);
            q.z = fmaf(a.z, a.z, q.z); q.w = fmaf(a.w, a.w, q.w);
        }
        ls[t] = s; lq[t] = q;
        __syncthreads();
        #pragma unroll
        for (int off = 128; off >= 32; off >>= 1) {
            if (t < off) {
                float4 a = ls[t], b = ls[t + off];
                ls[t] = make_float4(a.x + b.x, a.y + b.y, a.z + b.z, a.w + b.w);
                float4 c = lq[t], d = lq[t + off];
                lq[t] = make_float4(c.x + d.x, c.y + d.y, c.z + d.z, c.w + d.w);
            }
            __syncthreads();
        }
        if (t < 32) {
            float4* p4 = (float4*)(part + blockIdx.x * 256);
            p4[t] = ls[t];          // sum  cols 4t..4t+3
            p4[32 + t] = lq[t];     // sumsq
        }
    } else {
        int cb = blockIdx.x - 256;
        int c0 = cb * (CHUNK / 4);            // int4 index
        int c1 = min(E >> 2, c0 + CHUNK / 4);
        const int4* dst4 = (const int4*)dst;
        const int4* src4 = (const int4*)src;
        for (int i = t; i < NB; i += 256) hist[i] = 0;
        __syncthreads();
        for (int e = c0 + t; e < c1; e += 256) {
            int4 d = dst4[e];
            atomicAdd(&hist[d.x >> BSH], 1);
            atomicAdd(&hist[d.y >> BSH], 1);
            atomicAdd(&hist[d.z >> BSH], 1);
            atomicAdd(&hist[d.w >> BSH], 1);
        }
        __syncthreads();
        for (int i = t; i < NB; i += 256) {
            int h = hist[i];
            base[i] = h ? atomicAdd(&bnxt[i], h) : 0;
            hist[i] = 0;
        }
        __syncthreads();
        for (int e = c0 + t; e < c1; e += 256) {
            int4 d = dst4[e];
            int4 s = src4[e];
            int b, p;
            b = d.x >> BSH; p = base[b] + atomicAdd(&hist[b], 1); packed[b * CAP + p] = (s.x << BSH) | (d.x & (BSZ - 1));
            b = d.y >> BSH; p = base[b] + atomicAdd(&hist[b], 1); packed[b * CAP + p] = (s.y << BSH) | (d.y & (BSZ - 1));
            b = d.z >> BSH; p = base[b] + atomicAdd(&hist[b], 1); packed[b * CAP + p] = (s.z << BSH) | (d.z & (BSZ - 1));
            b = d.w >> BSH; p = base[b] + atomicAdd(&hist[b], 1); packed[b * CAP + p] = (s.w << BSH) | (d.w & (BSZ - 1));
        }
        if (cb == 0) {
            for (int e = (E & ~3) + t; e < E; e += 256) {
                int d = dst[e];
                int b = d >> BSH;
                int p = atomicAdd(&bnxt[b], 1);
                packed[b * CAP + p] = (src[e] << BSH) | (d & (BSZ - 1));
            }
        }
    }
}

// ---- stats pass 2: 8 blocks x 32 partial-rows -> part2[8][256] (no atomics) -----
__global__ __launch_bounds__(256) void k_stats2(const float* __restrict__ part,
    float* __restrict__ part2)
{
    int v = threadIdx.x;
    int b0 = blockIdx.x * 32;
    float s = 0.f;
    #pragma unroll 8
    for (int j = 0; j < 32; ++j) s += part[(b0 + j) * 256 + v];
    part2[blockIdx.x * 256 + v] = s;
}

// ---- fold BN into W1 (sums the 8 part2 rows inline; no atomics upstream) --------
__global__ __launch_bounds__(256) void k_foldW(const float* __restrict__ W1,
    const float* __restrict__ gamma, const float* __restrict__ beta,
    const float* __restrict__ part2, float invN,
    float* __restrict__ W1p, float* __restrict__ c1)
{
    int o = (blockIdx.x * 256 + threadIdx.x) >> 6;
    int l = threadIdx.x & 63;
    float part = 0.f;
    #pragma unroll
    for (int j = 0; j < 2; ++j) {
        int k = 2 * l + j;
        float sm = 0.f, sq = 0.f;
        #pragma unroll
        for (int b = 0; b < 8; ++b) {
            sm += part2[b * 256 + k];
            sq += part2[b * 256 + 128 + k];
        }
        float mu = sm * invN;
        float var = fmaf(-mu, mu, sq * invN);
        float sc = rsqrtf(var + EPSV) * gamma[k];
        float sh = fmaf(-mu, sc, beta[k]);
        float w = W1[o * NFEAT + k];
        W1p[o * NFEAT + k] = w * sc;
        part = fmaf(sh, w, part);
    }
    #pragma unroll
    for (int off = 32; off > 0; off >>= 1) part += __shfl_down(part, off);
    if (l == 0) c1[o] = part;
}

// ---- fused: internal bucket-scan -> per-bucket degree -> rp/dinv -> CSR place ---
__global__ __launch_bounds__(256) void k_bdp(const int* __restrict__ packed,
    const int* __restrict__ bnxt,
    int* __restrict__ rp, float* __restrict__ dinv,
    int* __restrict__ csr, int N, int E, int NB)
{
    __shared__ int cnt[BSZ];
    __shared__ int ps[256];
    __shared__ int pb[256];
    int b = blockIdx.x, t = threadIdx.x;
    cnt[2 * t] = 0; cnt[2 * t + 1] = 0;
    int v = (t < NB) ? bnxt[t] : 0;
    pb[t] = v;
    __syncthreads();
    #pragma unroll
    for (int off = 1; off < 256; off <<= 1) {
        int u = pb[t];
        if (t >= off) u += pb[t - off];
        __syncthreads();
        pb[t] = u;
        __syncthreads();
    }
    int boffb = (b == 0) ? 0 : pb[b - 1];      // exclusive prefix at b
    int ecnt = bnxt[b];
    const int* pk = packed + b * CAP;          // CAP%4==0 -> 16B aligned
    const int4* p4 = (const int4*)pk;
    int n4 = ecnt >> 2;
    // pass 1: count
    for (int e = t; e < n4; e += 256) {
        int4 w = p4[e];
        atomicAdd(&cnt[w.x & (BSZ - 1)], 1);
        atomicAdd(&cnt[w.y & (BSZ - 1)], 1);
        atomicAdd(&cnt[w.z & (BSZ - 1)], 1);
        atomicAdd(&cnt[w.w & (BSZ - 1)], 1);
    }
    for (int e = (n4 << 2) + t; e < ecnt; e += 256)
        atomicAdd(&cnt[pk[e] & (BSZ - 1)], 1);
    __syncthreads();
    int v0 = cnt[2 * t], v1 = cnt[2 * t + 1];
    int ts = v0 + v1;
    ps[t] = ts;
    __syncthreads();
    #pragma unroll
    for (int off = 1; off < 256; off <<= 1) {
        int u = ps[t];
        if (t >= off) u += ps[t - off];
        __syncthreads();
        ps[t] = u;
        __syncthreads();
    }
    int gbase = boffb + ps[t] - ts;
    cnt[2 * t] = gbase;            // becomes nxt
    cnt[2 * t + 1] = gbase + v0;
    int nbase = b << BSH;
    if (nbase + 2 * t < N) {
        rp[nbase + 2 * t] = gbase;
        dinv[nbase + 2 * t] = rsqrtf((float)(v0 + 1));
    }
    if (nbase + 2 * t + 1 < N) {
        rp[nbase + 2 * t + 1] = gbase + v0;
        dinv[nbase + 2 * t + 1] = rsqrtf((float)(v1 + 1));
    }
    if (b == 0 && t == 0) rp[N] = E;
    __syncthreads();
    // pass 2: place
    for (int e = t; e < n4; e += 256) {
        int4 w = p4[e];
        int p;
        p = atomicAdd(&cnt[w.x & (BSZ - 1)], 1); csr[p] = w.x >> BSH;
        p = atomicAdd(&cnt[w.y & (BSZ - 1)], 1); csr[p] = w.y >> BSH;
        p = atomicAdd(&cnt[w.z & (BSZ - 1)], 1); csr[p] = w.z >> BSH;
        p = atomicAdd(&cnt[w.w & (BSZ - 1)], 1); csr[p] = w.w >> BSH;
    }
    for (int e = (n4 << 2) + t; e < ecnt; e += 256) {
        int w = pk[e];
        int p = atomicAdd(&cnt[w & (BSZ - 1)], 1);
        csr[p] = w >> BSH;
    }
}

// ---- MFMA GEMM, f32 input: Y[n][o] = dinv[n]*((X[n]@W^T)[o] + C[o]) ------------
__global__ __launch_bounds__(256) void k_gemm_f32(const float4* __restrict__ X4,
    const float* __restrict__ W, const float* __restrict__ C,
    const float* __restrict__ dinv, _Float16* __restrict__ Y, int N)
{
    __shared__ _Float16 w16[NFEAT * 136];    // [o][k], row stride 136 halfs
    __shared__ _Float16 ost[4 * 16 * 136];   // 4 waves x 16 rows x 136 halfs
    const float4* W4 = (const float4*)W;
    for (int idx = threadIdx.x; idx < NFEAT * NFEAT / 4; idx += 256) {
        float4 w = W4[idx];
        int o = idx >> 5, k = (idx & 31) * 4;
        _Float16* d = &w16[o * 136 + k];
        d[0] = (_Float16)w.x; d[1] = (_Float16)w.y;
        d[2] = (_Float16)w.z; d[3] = (_Float16)w.w;
    }
    __syncthreads();

    const h8* Wv = (const h8*)w16;          // 17 h8-chunks per row
    h8* Yv = (h8*)Y;                         // 16 h8-chunks per row
    int lane = threadIdx.x & 63;
    int lr = lane & 15;
    int lk = lane >> 4;
    _Float16* slab = ost + (threadIdx.x >> 6) * (16 * 136);
    h8* slabv = (h8*)slab;
    int wid = (blockIdx.x * blockDim.x + threadIdx.x) >> 6;
    int nw = (gridDim.x * blockDim.x) >> 6;
    int ntiles = N >> 4;

    for (int tile = wid; tile < ntiles; tile += nw) {
        int r0 = tile << 4;
        h8 a[4];
        #pragma unroll
        for (int kg = 0; kg < 4; ++kg) {
            long fi = (long)(r0 + lr) * 32 + (kg * 4 + lk) * 2;
            float4 u = X4[fi];
            float4 v = X4[fi + 1];
            a[kg][0] = (_Float16)u.x; a[kg][1] = (_Float16)u.y;
            a[kg][2] = (_Float16)u.z; a[kg][3] = (_Float16)u.w;
            a[kg][4] = (_Float16)v.x; a[kg][5] = (_Float16)v.y;
            a[kg][6] = (_Float16)v.z; a[kg][7] = (_Float16)v.w;
        }

        f4 acc[8];
        #pragma unroll
        for (int nt = 0; nt < 8; ++nt) acc[nt] = (f4)(0.f);
        #pragma unroll
        for (int nt = 0; nt < 8; ++nt) {
            int o = nt * 16 + lr;
            #pragma unroll
            for (int kg = 0; kg < 4; ++kg) {
                h8 b = Wv[o * 17 + kg * 4 + lk];
                acc[nt] = __builtin_amdgcn_mfma_f32_16x16x32_f16(a[kg], b, acc[nt], 0, 0, 0);
            }
        }

        int rbase = lk * 4;
        float dv0 = dinv[r0 + rbase + 0];
        float dv1 = dinv[r0 + rbase + 1];
        float dv2 = dinv[r0 + rbase + 2];
        float dv3 = dinv[r0 + rbase + 3];
        #pragma unroll
        for (int nt = 0; nt < 8; ++nt) {
            int c = nt * 16 + lr;
            float cb = C[c];
            slab[(rbase + 0) * 136 + c] = (_Float16)((acc[nt][0] + cb) * dv0);
            slab[(rbase + 1) * 136 + c] = (_Float16)((acc[nt][1] + cb) * dv1);
            slab[(rbase + 2) * 136 + c] = (_Float16)((acc[nt][2] + cb) * dv2);
            slab[(rbase + 3) * 136 + c] = (_Float16)((acc[nt][3] + cb) * dv3);
        }
        #pragma unroll
        for (int j = 0; j < 4; ++j) {
            int row = j * 4 + lk;
            Yv[(long)(r0 + row) * 16 + lr] = slabv[row * 17 + lr];
        }
    }
}

// ---- MFMA GEMM, f16 input (layer 2): Y[n][o] = dinv[n]*(X[n]@W^T)[o] -----------
__global__ __launch_bounds__(256) void k_gemm_f16(const _Float16* __restrict__ X,
    const float* __restrict__ W, const float* __restrict__ dinv,
    _Float16* __restrict__ Y, int N)
{
    __shared__ _Float16 w16[NFEAT * 136];
    __shared__ _Float16 ost[4 * 16 * 136];
    const float4* W4 = (const float4*)W;
    for (int idx = threadIdx.x; idx < NFEAT * NFEAT / 4; idx += 256) {
        float4 w = W4[idx];
        int o = idx >> 5, k = (idx & 31) * 4;
        _Float16* d = &w16[o * 136 + k];
        d[0] = (_Float16)w.x; d[1] = (_Float16)w.y;
        d[2] = (_Float16)w.z; d[3] = (_Float16)w.w;
    }
    __syncthreads();

    const h8* Xv = (const h8*)X;
    const h8* Wv = (const h8*)w16;
    h8* Yv = (h8*)Y;
    int lane = threadIdx.x & 63;
    int lr = lane & 15;
    int lk = lane >> 4;
    _Float16* slab = ost + (threadIdx.x >> 6) * (16 * 136);
    h8* slabv = (h8*)slab;
    int wid = (blockIdx.x * blockDim.x + threadIdx.x) >> 6;
    int nw = (gridDim.x * blockDim.x) >> 6;
    int ntiles = N >> 4;

    for (int tile = wid; tile < ntiles; tile += nw) {
        int r0 = tile << 4;
        h8 a[4];
        #pragma unroll
        for (int kg = 0; kg < 4; ++kg)
            a[kg] = Xv[(long)(r0 + lr) * 16 + kg * 4 + lk];

        f4 acc[8];
        #pragma unroll
        for (int nt = 0; nt < 8; ++nt) acc[nt] = (f4)(0.f);
        #pragma unroll
        for (int nt = 0; nt < 8; ++nt) {
            int o = nt * 16 + lr;
            #pragma unroll
            for (int kg = 0; kg < 4; ++kg) {
                h8 b = Wv[o * 17 + kg * 4 + lk];
                acc[nt] = __builtin_amdgcn_mfma_f32_16x16x32_f16(a[kg], b, acc[nt], 0, 0, 0);
            }
        }

        int rbase = lk * 4;
        float dv0 = dinv[r0 + rbase + 0];
        float dv1 = dinv[r0 + rbase + 1];
        float dv2 = dinv[r0 + rbase + 2];
        float dv3 = dinv[r0 + rbase + 3];
        #pragma unroll
        for (int nt = 0; nt < 8; ++nt) {
            int c = nt * 16 + lr;
            slab[(rbase + 0) * 136 + c] = (_Float16)(acc[nt][0] * dv0);
            slab[(rbase + 1) * 136 + c] = (_Float16)(acc[nt][1] * dv1);
            slab[(rbase + 2) * 136 + c] = (_Float16)(acc[nt][2] * dv2);
            slab[(rbase + 3) * 136 + c] = (_Float16)(acc[nt][3] * dv3);
        }
        #pragma unroll
        for (int j = 0; j < 4; ++j) {
            int row = j * 4 + lk;
            Yv[(long)(r0 + row) * 16 + lr] = slabv[row * 17 + lr];
        }
    }
}

// ---------------- aggregation: one wave per dst node; 16/8/1 gather unroll -------
__global__ __launch_bounds__(256) void k_agg(const unsigned int* __restrict__ TT,
    const int* __restrict__ rp, const int* __restrict__ csr,
    const float* __restrict__ dinv, const float* __restrict__ bias,
    unsigned int* __restrict__ OUT, int N)
{
    int wid = (blockIdx.x * 256 + threadIdx.x) >> 6;
    if (wid >= N) return;
    int lane = threadIdx.x & 63;
    unsigned int sv = TT[wid * 64 + lane];
    float2 acc = __half22float2(*(const __half2*)&sv);   // self-loop term
    int e = rp[wid], e1 = rp[wid + 1];
    for (; e + 16 <= e1; e += 16) {
        int si[16];
        #pragma unroll
        for (int j = 0; j < 16; ++j) si[j] = csr[e + j];
        unsigned int v[16];
        #pragma unroll
        for (int j = 0; j < 16; ++j) v[j] = TT[si[j] * 64 + lane];
        float ax = 0.f, ay = 0.f;
        #pragma unroll
        for (int j = 0; j < 16; ++j) {
            float2 f = __half22float2(*(const __half2*)&v[j]);
            ax += f.x; ay += f.y;
        }
        acc.x += ax; acc.y += ay;
    }
    for (; e + 8 <= e1; e += 8) {
        int s0 = csr[e + 0], s1 = csr[e + 1], s2 = csr[e + 2], s3 = csr[e + 3];
        int s4 = csr[e + 4], s5 = csr[e + 5], s6 = csr[e + 6], s7 = csr[e + 7];
        unsigned int v0 = TT[s0 * 64 + lane];
        unsigned int v1 = TT[s1 * 64 + lane];
        unsigned int v2 = TT[s2 * 64 + lane];
        unsigned int v3 = TT[s3 * 64 + lane];
        unsigned int v4 = TT[s4 * 64 + lane];
        unsigned int v5 = TT[s5 * 64 + lane];
        unsigned int v6 = TT[s6 * 64 + lane];
        unsigned int v7 = TT[s7 * 64 + lane];
        float2 f0 = __half22float2(*(const __half2*)&v0);
        float2 f1 = __half22float2(*(const __half2*)&v1);
        float2 f2 = __half22float2(*(const __half2*)&v2);
        float2 f3 = __half22float2(*(const __half2*)&v3);
        float2 f4_ = __half22float2(*(const __half2*)&v4);
        float2 f5 = __half22float2(*(const __half2*)&v5);
        float2 f6 = __half22float2(*(const __half2*)&v6);
        float2 f7 = __half22float2(*(const __half2*)&v7);
        acc.x += ((f0.x + f1.x) + (f2.x + f3.x)) + ((f4_.x + f5.x) + (f6.x + f7.x));
        acc.y += ((f0.y + f1.y) + (f2.y + f3.y)) + ((f4_.y + f5.y) + (f6.y + f7.y));
    }
    for (; e < e1; ++e) {
        int s = csr[e];
        unsigned int v = TT[s * 64 + lane];
        float2 f = __half22float2(*(const __half2*)&v);
        acc.x += f.x; acc.y += f.y;
    }
    float dv = dinv[wid];
    float ox = fmaxf(fmaf(acc.x, dv, bias[lane * 2 + 0]), 0.f);
    float oy = fmaxf(fmaf(acc.y, dv, bias[lane * 2 + 1]), 0.f);
    __half2 o2 = __floats2half2_rn(ox, oy);
    OUT[wid * 64 + lane] = *(unsigned int*)&o2;
}

// ---------------- fused head: relu(H@Wc1^T + bc1) @ Wc2^T + bc2  (H f16) ---------
__global__ __launch_bounds__(256) void k_head(const __half* __restrict__ H,
    const float* __restrict__ Wc1, const float* __restrict__ bc1,
    const float* __restrict__ Wc2, const float* __restrict__ bc2,
    float* __restrict__ OUT, int N)
{
    __shared__ float w1[16][132];
    __shared__ float hs[16][132];
    __shared__ float h16[16][17];
    const float4* Wc14 = (const float4*)Wc1;
    for (int idx = threadIdx.x; idx < 16 * NFEAT / 4; idx += 256) {
        float4 w = Wc14[idx];
        int o = idx >> 5, k = (idx & 31) * 4;
        w1[o][k] = w.x; w1[o][k + 1] = w.y; w1[o][k + 2] = w.z; w1[o][k + 3] = w.w;
    }
    const uint4* Hu4 = (const uint4*)H;     // 16 uint4 per 128-f16 row
    int ntiles = (N + 15) >> 4;
    for (int tile = blockIdx.x; tile < ntiles; tile += gridDim.x) {
        int row0 = tile << 4;
        __syncthreads();   // also covers w1 init on first iter
        {
            int r = threadIdx.x >> 4, p = threadIdx.x & 15;
            int row = row0 + r;
            uint4 v = (row < N) ? Hu4[(long)row * 16 + p] : make_uint4(0, 0, 0, 0);
            float2 f0 = __half22float2(*(const __half2*)&v.x);
            float2 f1 = __half22float2(*(const __half2*)&v.y);
            float2 f2 = __half22float2(*(const __half2*)&v.z);
            float2 f3 = __half22float2(*(const __half2*)&v.w);
            int c = p * 8;
            hs[r][c + 0] = f0.x; hs[r][c + 1] = f0.y;
            hs[r][c + 2] = f1.x; hs[r][c + 3] = f1.y;
            hs[r][c + 4] = f2.x; hs[r][c + 5] = f2.y;
            hs[r][c + 6] = f3.x; hs[r][c + 7] = f3.y;
        }
        __syncthreads();
        int r = threadIdx.x >> 4, o = threadIdx.x & 15;
        float acc = 0.f;
        #pragma unroll 8
        for (int k = 0; k < NFEAT; ++k) acc = fmaf(hs[r][k], w1[o][k], acc);
        h16[r][o] = fmaxf(acc + bc1[o], 0.f);
        __syncthreads();
        if (threadIdx.x < 32) {
            int rr = threadIdx.x >> 1, j = threadIdx.x & 1;
            float a = bc2[j];
            #pragma unroll
            for (int o2 = 0; o2 < 16; ++o2) a = fmaf(h16[rr][o2], Wc2[j * 16 + o2], a);
            int row = row0 + rr;
            if (row < N) OUT[(long)row * 2 + j] = a;
        }
        __syncthreads();
    }
}

extern "C" void kernel_launch(void* const* d_in, const int* in_sizes, int n_in,
                              void* d_out, int out_size, void* d_ws, size_t ws_size,
                              hipStream_t stream) {
    const float* x     = (const float*)d_in[0];
    const int*   ei    = (const int*)d_in[1];
    const float* gamma = (const float*)d_in[2];
    const float* beta  = (const float*)d_in[3];
    const float* W1    = (const float*)d_in[4];
    const float* b1    = (const float*)d_in[5];
    const float* W2    = (const float*)d_in[6];
    const float* b2    = (const float*)d_in[7];
    const float* Wc1   = (const float*)d_in[8];
    const float* bc1   = (const float*)d_in[9];
    const float* Wc2   = (const float*)d_in[10];
    const float* bc2   = (const float*)d_in[11];

    int N = in_sizes[0] / NFEAT;
    int E = in_sizes[1] / 2;
    const int* srcI = ei;
    const int* dstI = ei + E;
    int NB = (N + BSZ - 1) >> BSH;   // 196 for N=100k (<=256 required)

    char* ws = (char*)d_ws;
    size_t off = 0;
    auto alloc = [&](size_t bytes) {
        void* p = ws + off;
        off += bytes;
        off = (off + 511) & ~(size_t)511;
        return p;
    };
    __half* bufA  = (__half*)alloc((size_t)N * NFEAT * 2);   // h buffer
    __half* bufB  = (__half*)alloc((size_t)N * NFEAT * 2);   // tt buffer
    float* part   = (float*)alloc(256 * 256 * 4);            // stats partials
    float* part2  = (float*)alloc(8 * 256 * 4);              // stats partials lvl2
    float* W1p    = (float*)alloc(NFEAT * NFEAT * 4);
    float* c1     = (float*)alloc(NFEAT * 4);
    int*   rp     = (int*)alloc((size_t)(N + 1) * 4);
    float* dinv   = (float*)alloc((size_t)N * 4);
    int*   csr    = (int*)alloc((size_t)E * 4);
    int*   packed = (int*)alloc((size_t)NB * CAP * 4);
    int*   bnxt   = (int*)alloc((size_t)(NB + 1) * 4);
    (void)ws_size;

    hipMemsetAsync(bnxt, 0, (size_t)(NB + 1) * 4, stream);

    int total4 = (int)((long)N * NFEAT / 4);
    int nchunk = (E + CHUNK - 1) / CHUNK;
    int naggb = (N + 3) / 4;

    // front: stats (256 blocks) || bucket (nchunk blocks)
    k_front<<<256 + nchunk, 256, 0, stream>>>((const float4*)x, part, total4,
                                              srcI, dstI, bnxt, packed, E, NB);
    k_stats2<<<8, 256, 0, stream>>>(part, part2);
    k_foldW<<<32, 256, 0, stream>>>(W1, gamma, beta, part2, 1.0f / (float)N, W1p, c1);
    k_bdp<<<NB, 256, 0, stream>>>(packed, bnxt, rp, dinv, csr, N, E, NB);

    // layer 1 (BN folded into W1p/c1; reads f32 x directly)
    k_gemm_f32<<<512, 256, 0, stream>>>((const float4*)x, W1p, c1, dinv, (_Float16*)bufB, N);
    k_agg<<<naggb, 256, 0, stream>>>((const unsigned int*)bufB, rp, csr, dinv, b1, (unsigned int*)bufA, N);
    // layer 2
    k_gemm_f16<<<512, 256, 0, stream>>>((const _Float16*)bufA, W2, dinv, (_Float16*)bufB, N);
    k_agg<<<naggb, 256, 0, stream>>>((const unsigned int*)bufB, rp, csr, dinv, b2, (unsigned int*)bufA, N);
    // head
    k_head<<<2048, 256, 0, stream>>>(bufA, Wc1, bc1, Wc2, bc2, (float*)d_out, N);
}